// Round 5
// baseline (194.624 us; speedup 1.0000x reference)
//
#include <hip/hip_runtime.h>
#include <cmath>

#define EPS 1e-5f
#define SZ 2097152  // N*H*W*E = 4*64*64*128

typedef __attribute__((ext_vector_type(8))) short short8;   // 8 bf16 (4 VGPRs)
typedef __attribute__((ext_vector_type(4))) float floatx4;  // MFMA C/D frag

__device__ __forceinline__ float dot4(float4 a, float4 b) {
  return fmaf(a.x, b.x, fmaf(a.y, b.y, fmaf(a.z, b.z, a.w * b.w)));
}

__device__ __forceinline__ short f2bf(float f) {
  union { float f; unsigned u; } v; v.f = f;
  unsigned r = v.u + 0x7fff + ((v.u >> 16) & 1);  // RNE
  return (short)(r >> 16);
}

#define MFMA16(a, b, c) __builtin_amdgcn_mfma_f32_16x16x32_bf16(a, b, c, 0, 0, 0)

// ---------------------------------------------------------------- K0: weight prep (fp32 -> bf16, padded 136 rows)
// grid 64, block 256
__global__ __launch_bounds__(256) void k_prep(const float* __restrict__ w1,
    const float* __restrict__ w2, const float* __restrict__ wq,
    const float* __restrict__ wk, const float* __restrict__ wv,
    short* __restrict__ w1bf, short* __restrict__ w2bf,
    short* __restrict__ wqbf, short* __restrict__ wkbf, short* __restrict__ wvbf) {
  int tid0 = blockIdx.x * 256 + threadIdx.x;
  int stride = gridDim.x * 256;
  // w1 [512f][128c] -> [512][136]
  for (int i = tid0; i < 16384; i += stride) {
    int flat = i * 4; int f = flat >> 7, c = flat & 127;
    float4 v = *(const float4*)&w1[flat];
    short t4[4] = {f2bf(v.x), f2bf(v.y), f2bf(v.z), f2bf(v.w)};
    *(uint2*)&w1bf[f * 136 + c] = *(uint2*)t4;
  }
  // w2 [128o][512j] -> 4 chunks of [128o][136]
  for (int i = tid0; i < 16384; i += stride) {
    int flat = i * 4; int o = flat >> 9, j = flat & 511;
    int ck = j >> 7, jj = j & 127;
    float4 v = *(const float4*)&w2[flat];
    short t4[4] = {f2bf(v.x), f2bf(v.y), f2bf(v.z), f2bf(v.w)};
    *(uint2*)&w2bf[(ck * 128 + o) * 136 + jj] = *(uint2*)t4;
  }
  // wq/wk/wv [128o][128c] -> [128][136]
  for (int i = tid0; i < 4096; i += stride) {
    int flat = i * 4; int o = flat >> 7, c = flat & 127;
    float4 a = *(const float4*)&wq[flat];
    float4 b = *(const float4*)&wk[flat];
    float4 cc = *(const float4*)&wv[flat];
    short ta[4] = {f2bf(a.x), f2bf(a.y), f2bf(a.z), f2bf(a.w)};
    short tb4[4] = {f2bf(b.x), f2bf(b.y), f2bf(b.z), f2bf(b.w)};
    short tc[4] = {f2bf(cc.x), f2bf(cc.y), f2bf(cc.z), f2bf(cc.w)};
    *(uint2*)&wqbf[o * 136 + c] = *(uint2*)ta;
    *(uint2*)&wkbf[o * 136 + c] = *(uint2*)tb4;
    *(uint2*)&wvbf[o * 136 + c] = *(uint2*)tc;
  }
}

// ---------------------------------------------------------------- K1: LN1 + transpose
// grid 256 = (n*64+y), block 256
__global__ __launch_bounds__(256) void k_ln1(const float* __restrict__ x,
    const float* __restrict__ g, const float* __restrict__ b,
    float* __restrict__ xnhwc, float* __restrict__ xn) {
  __shared__ float tile[128 * 65];
  __shared__ float mres[64], rres[64];
  int bid = blockIdx.x;
  int n = bid >> 6, y = bid & 63;
  const float* xb = x + (size_t)n * (128 * 64 * 64) + y * 64;
  int tid = threadIdx.x;
  for (int it = 0; it < 32; ++it) {
    int flat = it * 256 + tid;            // 8192 = 128c * 64x
    int c = flat >> 6, xp = flat & 63;
    tile[c * 65 + xp] = xb[(size_t)c * 4096 + xp];
  }
  __syncthreads();
  if (tid < 64) {
    float s = 0.f, sq = 0.f;
    for (int c = 0; c < 128; ++c) { float v = tile[c * 65 + tid]; s += v; sq += v * v; }
    float m = s * (1.f / 128.f);
    float var = sq * (1.f / 128.f) - m * m;
    mres[tid] = m;
    rres[tid] = rsqrtf(var + EPS);
  }
  __syncthreads();
  size_t rowbase = (size_t)bid * (64 * 128);
  for (int it = 0; it < 32; ++it) {
    int flat = it * 256 + tid;            // = px*128 + c
    int c = flat & 127, px = flat >> 7;
    float v = tile[c * 65 + px];
    xnhwc[rowbase + flat] = v;
    xn[rowbase + flat] = (v - mres[px]) * rres[px] * g[c] + b[c];
  }
}

// ---------------------------------------------------------------- K2: QKV projection (MFMA bf16)
// grid 256 = (n*64+y), block 1024 = 16 waves; wave = (wm = 16-px strip, wn = 32-wide o quarter)
__global__ __launch_bounds__(1024) void k_qkv(const float* __restrict__ xn,
    const short* __restrict__ wqbf, const short* __restrict__ wkbf,
    const short* __restrict__ wvbf, const float* __restrict__ bq,
    const float* __restrict__ bk, const float* __restrict__ bv,
    float* __restrict__ q, float* __restrict__ k, float* __restrict__ v) {
  __shared__ __align__(16) short xs[64 * 136];   // A: [px][c]
  __shared__ __align__(16) short ws[128 * 136];  // B: [o][c]
  int tid = threadIdx.x;
  size_t rowbase = (size_t)blockIdx.x * (64 * 128);
  for (int it = 0; it < 2; ++it) {
    int flat = (it * 1024 + tid) * 4;
    int px = flat >> 7, c = flat & 127;
    float4 xv = *(const float4*)&xn[rowbase + flat];
    short tmp[4] = {f2bf(xv.x), f2bf(xv.y), f2bf(xv.z), f2bf(xv.w)};
    *(uint2*)&xs[px * 136 + c] = *(uint2*)tmp;
  }
  __syncthreads();
  int w = tid >> 6, lane = tid & 63;
  int quad = lane >> 4, r16 = lane & 15;
  int wm = w & 3, wn = w >> 2;
  int strip = wm * 16;
  short8 a[4];
#pragma unroll
  for (int kk = 0; kk < 4; ++kk)
    a[kk] = *(const short8*)&xs[(strip + r16) * 136 + kk * 32 + quad * 8];
  const short* wptr[3] = {wqbf, wkbf, wvbf};
  const float* bptr[3] = {bq, bk, bv};
  float* optr[3] = {q, k, v};
  for (int m = 0; m < 3; ++m) {
    __syncthreads();   // previous matrix's B-frag readers done
    const short* wp = wptr[m];
    for (int i = tid; i < 2176; i += 1024)
      *(short8*)&ws[i * 8] = *(const short8*)&wp[i * 8];
    __syncthreads();
    const float* bb = bptr[m];
    float* op = optr[m];
#pragma unroll
    for (int nt = 0; nt < 2; ++nt) {
      int o0 = wn * 32 + nt * 16;
      floatx4 acc = {0.f, 0.f, 0.f, 0.f};
#pragma unroll
      for (int kk = 0; kk < 4; ++kk) {
        short8 bfr = *(const short8*)&ws[(o0 + r16) * 136 + kk * 32 + quad * 8];
        acc = MFMA16(a[kk], bfr, acc);
      }
      float bv2 = bb[o0 + r16];
#pragma unroll
      for (int r = 0; r < 4; ++r) {
        int px = strip + quad * 4 + r;
        op[rowbase + px * 128 + o0 + r16] = acc[r] + bv2;
      }
    }
  }
}

// ---------------------------------------------------------------- K3: local-window attention (MFMA, banded, barrier-light)
// grid 1024 = ((n*64+y)*4+h), block 256 = 4 waves; wave w owns px strip [16w,16w+16)
__global__ __launch_bounds__(256) void k_attn(const float* __restrict__ qb,
    const float* __restrict__ kb, const float* __restrict__ vb,
    const float* __restrict__ rel_bias, float* __restrict__ z0) {
  // LDS: KV union (Ks [7][80][40] 44800 / Vt [7][32][104] 46592) | ssf [64][52] f32 | Abw 4x[16][68] | bias
  __shared__ __align__(16) char smem[46592 + 13312 + 8704 + 256];
  short* KV = (short*)smem;
  float* ssf = (float*)(smem + 46592);
  short* AbB = (short*)(smem + 46592 + 13312);
  float* bias = (float*)(smem + 46592 + 13312 + 8704);

  int bid = blockIdx.x;
  int h = bid & 3, y = (bid >> 2) & 63, n = bid >> 8;
  int tid = threadIdx.x;
  size_t base_nh = (size_t)n * (64 * 64 * 128) + h * 32;
  const float* qrow = qb + base_nh + (size_t)y * 64 * 128;

  int w = tid >> 6, lane = tid & 63;
  int quad = lane >> 4, r16 = lane & 15;
  int strip = w * 16;
  short* Abw = AbB + w * (16 * 68);   // wave-private banded A strip [16 rows][68 cols]

  // zero wave-private Ab strip (single-writer/single-reader: no barrier needed)
  {
    unsigned* ad = (unsigned*)Abw;
    for (int i = lane; i < 544; i += 64) ad[i] = 0u;
  }
  // Q fragment direct from global (A[m=px][k=d])
  short8 qf;
  {
    const float* qp = qrow + (strip + r16) * 128 + quad * 8;
    float4 v0 = *(const float4*)qp;
    float4 v1 = *(const float4*)(qp + 4);
    short t8[8] = {f2bf(v0.x), f2bf(v0.y), f2bf(v0.z), f2bf(v0.w),
                   f2bf(v1.x), f2bf(v1.y), f2bf(v1.z), f2bf(v1.w)};
    qf = *(short8*)t8;
  }
  // stage K window rows -> Ks[r][xx][d], zero outside image (matches reference pad)
  for (int r = 0; r < 7; ++r) {
    int yy = y + r - 3;
    for (int i = tid; i < 560; i += 256) {  // 70xx * 8d4
      int xx = i >> 3, d4 = i & 7;
      int gx = xx - 3;
      float4 v = make_float4(0.f, 0.f, 0.f, 0.f);
      if (yy >= 0 && yy < 64 && gx >= 0 && gx < 64)
        v = *(const float4*)&kb[base_nh + (size_t)(yy * 64 + gx) * 128 + d4 * 4];
      short t4[4] = {f2bf(v.x), f2bf(v.y), f2bf(v.z), f2bf(v.w)};
      *(uint2*)&KV[(r * 80 + xx) * 40 + d4 * 4] = *(uint2*)t4;
    }
  }
  if (tid < 49) bias[tid] = rel_bias[h * 49 + tid];
  __syncthreads();

  // QK^T: 2 N-tiles intersecting this strip's band
#pragma unroll
  for (int r = 0; r < 7; ++r) {
#pragma unroll
    for (int t = 0; t < 2; ++t) {
      int xxc = (w + t) * 16 + r16;
      short8 bf = *(const short8*)&KV[(r * 80 + xxc) * 40 + quad * 8];
      floatx4 c = MFMA16(qf, bf, ((floatx4){0.f, 0.f, 0.f, 0.f}));
#pragma unroll
      for (int rr = 0; rr < 4; ++rr) {
        int px = strip + quad * 4 + rr;
        int dx = xxc - px;
        if ((unsigned)dx < 7u) ssf[px * 52 + r * 7 + dx] = c[rr] + bias[r * 7 + dx];
      }
    }
  }
  __syncthreads();
  // stage V^T -> Vt[r][d][xx] (overwrites Ks), zero pad xx in [70,96)
  for (int r = 0; r < 7; ++r) {
    int yy = y + r - 3;
    for (int i = tid; i < 560; i += 256) {
      int xx = i >> 3, d4 = i & 7;
      int gx = xx - 3;
      float4 v = make_float4(0.f, 0.f, 0.f, 0.f);
      if (yy >= 0 && yy < 64 && gx >= 0 && gx < 64)
        v = *(const float4*)&vb[base_nh + (size_t)(yy * 64 + gx) * 128 + d4 * 4];
      KV[(r * 32 + d4 * 4 + 0) * 104 + xx] = f2bf(v.x);
      KV[(r * 32 + d4 * 4 + 1) * 104 + xx] = f2bf(v.y);
      KV[(r * 32 + d4 * 4 + 2) * 104 + xx] = f2bf(v.z);
      KV[(r * 32 + d4 * 4 + 3) * 104 + xx] = f2bf(v.w);
    }
  }
  {
    unsigned* kvd = (unsigned*)KV;           // rows are 52 dwords; zero dwords 35..47 (xx 70..95)
    for (int i = tid; i < 7 * 32 * 13; i += 256) {
      int row = i / 13, xd = i - row * 13;
      kvd[row * 52 + 35 + xd] = 0u;
    }
  }
  // softmax over 49 positions (wave-local px rows: tid>>2 in [strip, strip+16))
  {
    int px = tid >> 2, sub = tid & 3;
    int p0 = sub * 12, cnt = (sub == 3) ? 13 : 12;
    float sv[13];
    float mx = -1e30f;
    for (int pi = 0; pi < cnt; ++pi) { sv[pi] = ssf[px * 52 + p0 + pi]; mx = fmaxf(mx, sv[pi]); }
    mx = fmaxf(mx, __shfl_xor(mx, 1));
    mx = fmaxf(mx, __shfl_xor(mx, 2));
    float sum = 0.f;
    for (int pi = 0; pi < cnt; ++pi) { float e = __expf(sv[pi] - mx); sv[pi] = e; sum += e; }
    sum += __shfl_xor(sum, 1);
    sum += __shfl_xor(sum, 2);
    float inv = 1.f / sum;
    for (int pi = 0; pi < cnt; ++pi) ssf[px * 52 + p0 + pi] = sv[pi] * inv;
  }
  __syncthreads();   // Vt visible to all waves (softmaxed ssf rows are wave-local)
  // PV: wave-private banded A strip, NO barriers in the loop
  floatx4 oacc[2] = {(floatx4){0.f, 0.f, 0.f, 0.f}, (floatx4){0.f, 0.f, 0.f, 0.f}};
  int kbase = strip & 96;               // 0,0,32,32 for strips 0,16,32,48
  int off = strip - kbase;              // 0 or 16
  int nchunks = (strip & 16) ? 2 : 1;   // band cols <= off+22 -> 1 or 2 k-chunks
  int lrow = (lane >> 2), sub = lane & 3;
  for (int r = 0; r < 7; ++r) {
    // scatter this r's 7 band values into wave-private strip (local col = off + lrow + dx)
    Abw[lrow * 68 + off + lrow + sub] = f2bf(ssf[(strip + lrow) * 52 + r * 7 + sub]);
    if (sub < 3)
      Abw[lrow * 68 + off + lrow + sub + 4] = f2bf(ssf[(strip + lrow) * 52 + r * 7 + sub + 4]);
    for (int kk = 0; kk < nchunks; ++kk) {
      short8 af = *(const short8*)&Abw[r16 * 68 + kk * 32 + quad * 8];
#pragma unroll
      for (int nt = 0; nt < 2; ++nt) {
        short8 vf = *(const short8*)&KV[(r * 32 + nt * 16 + r16) * 104 + kbase + kk * 32 + quad * 8];
        oacc[nt] = MFMA16(af, vf, oacc[nt]);
      }
    }
  }
  // epilogue: C[px][d] -> z0
  float* zrow = z0 + base_nh + (size_t)y * 64 * 128;
#pragma unroll
  for (int nt = 0; nt < 2; ++nt)
#pragma unroll
    for (int rr = 0; rr < 4; ++rr) {
      int px = strip + quad * 4 + rr;
      zrow[px * 128 + nt * 16 + r16] = oacc[nt][rr];
    }
}

// ---------------------------------------------------------------- K4: t = bil_w . qcoeff -> bf16 (padded 136)
// grid 64, block 256
__global__ __launch_bounds__(256) void k_t(const float* __restrict__ bil_w,
    const float* __restrict__ qcoeff, short* __restrict__ t) {
  __shared__ float qs[4 * 64];
  int tid = threadIdx.x;
  qs[tid] = qcoeff[tid];
  __syncthreads();
  int flat = blockIdx.x * 256 + tid;          // o*128 + i
  const float* wrow = bil_w + (size_t)flat * 64;
  float acc[4] = {0.f, 0.f, 0.f, 0.f};
  for (int qq = 0; qq < 64; qq += 4) {
    float4 w4 = *(const float4*)&wrow[qq];
#pragma unroll
    for (int nn = 0; nn < 4; ++nn) {
      const float* qc = &qs[nn * 64 + qq];
      acc[nn] = fmaf(w4.x, qc[0], fmaf(w4.y, qc[1], fmaf(w4.z, qc[2], fmaf(w4.w, qc[3], acc[nn]))));
    }
  }
  int o = flat >> 7, i = flat & 127;
#pragma unroll
  for (int nn = 0; nn < 4; ++nn) t[nn * 17408 + o * 136 + i] = f2bf(acc[nn]);
}

// ---------------------------------------------------------------- K5: bilinear (MFMA) + residual + LN2
// grid 256 = (n*64+y), block 1024 = 16 waves
__global__ __launch_bounds__(1024) void k_bil(const float* __restrict__ z0,
    const short* __restrict__ tb, const float* __restrict__ bil_b,
    const float* __restrict__ xnhwc, const float* __restrict__ g2,
    const float* __restrict__ b2ln, float* __restrict__ z2,
    float* __restrict__ z3) {
  __shared__ __align__(16) short zs[64 * 136];
  __shared__ __align__(16) short ts[128 * 136];
  __shared__ __align__(16) float z2s[64 * 132];
  int tid = threadIdx.x;
  int bid = blockIdx.x;
  int n = bid >> 6;
  size_t rowbase = (size_t)bid * (64 * 128);
  for (int it = 0; it < 2; ++it) {
    int flat = (it * 1024 + tid) * 4;
    int px = flat >> 7, c = flat & 127;
    float4 v = *(const float4*)&z0[rowbase + flat];
    short tmp[4] = {f2bf(v.x), f2bf(v.y), f2bf(v.z), f2bf(v.w)};
    *(uint2*)&zs[px * 136 + c] = *(uint2*)tmp;
  }
  const short* tn = tb + (size_t)n * 17408;
  for (int i = tid; i < 2176; i += 1024)
    *(short8*)&ts[i * 8] = *(const short8*)&tn[i * 8];
  __syncthreads();
  int w = tid >> 6, lane = tid & 63;
  int quad = lane >> 4, r16 = lane & 15;
  int wm = w & 3, wn = w >> 2;
  int strip = wm * 16;
  short8 a[4];
#pragma unroll
  for (int kk = 0; kk < 4; ++kk)
    a[kk] = *(const short8*)&zs[(strip + r16) * 136 + kk * 32 + quad * 8];
#pragma unroll
  for (int nt = 0; nt < 2; ++nt) {
    int o0 = wn * 32 + nt * 16;
    floatx4 acc = {0.f, 0.f, 0.f, 0.f};
#pragma unroll
    for (int kk = 0; kk < 4; ++kk) {
      short8 bfr = *(const short8*)&ts[(o0 + r16) * 136 + kk * 32 + quad * 8];
      acc = MFMA16(a[kk], bfr, acc);
    }
    float bb = bil_b[o0 + r16];
#pragma unroll
    for (int r = 0; r < 4; ++r) {
      int px = strip + quad * 4 + r;
      z2s[px * 132 + o0 + r16] = acc[r] + bb + xnhwc[rowbase + px * 128 + o0 + r16];
    }
  }
  __syncthreads();
  // LN2: 16 lanes per px
  {
    int px = tid >> 4, cl = tid & 15;
    float4 v0 = *(const float4*)&z2s[px * 132 + cl * 8];
    float4 v1 = *(const float4*)&z2s[px * 132 + cl * 8 + 4];
    float s = v0.x + v0.y + v0.z + v0.w + v1.x + v1.y + v1.z + v1.w;
    float sq = dot4(v0, v0) + dot4(v1, v1);
    s += __shfl_xor(s, 1);  sq += __shfl_xor(sq, 1);
    s += __shfl_xor(s, 2);  sq += __shfl_xor(sq, 2);
    s += __shfl_xor(s, 4);  sq += __shfl_xor(sq, 4);
    s += __shfl_xor(s, 8);  sq += __shfl_xor(sq, 8);
    float m = s * (1.f / 128.f);
    float var = sq * (1.f / 128.f) - m * m;
    float rr = rsqrtf(var + EPS);
    int c0 = cl * 8;
    float o0v[8];
#pragma unroll
    for (int j = 0; j < 8; ++j) {
      float vv = (j < 4) ? (&v0.x)[j] : (&v1.x)[j - 4];
      o0v[j] = vv;
    }
    float* z2p = &z2[rowbase + px * 128 + c0];
    float* z3p = &z3[rowbase + px * 128 + c0];
#pragma unroll
    for (int j = 0; j < 8; ++j) {
      z2p[j] = o0v[j];
      z3p[j] = (o0v[j] - m) * rr * g2[c0 + j] + b2ln[c0 + j];
    }
  }
}

// ---------------------------------------------------------------- K6: FFN (MFMA) + residual + NCHW
// grid 256 = (n*64+y), block 1024 = 16 waves; f-chunks of 128
__global__ __launch_bounds__(1024) void k_ffn(const float* __restrict__ z3,
    const float* __restrict__ z2, const short* __restrict__ w1bf,
    const float* __restrict__ b1, const short* __restrict__ w2bf,
    const float* __restrict__ b2, float* __restrict__ out) {
  __shared__ __align__(16) char smem[17408 + 34816 + 17408 + 34816];
  short* z3s = (short*)smem;                          // [64px][136c]
  short* w1c = (short*)(smem + 17408);                // [128f][136c]
  short* h1s = (short*)(smem + 17408 + 34816);        // [64px][136f]
  short* w2c = (short*)(smem + 17408 + 34816 + 17408);// [128o][136j]
  float* outt = (float*)(smem + 17408);               // [128o][65px] fp32 (aliases w1c)
  int tid = threadIdx.x;
  int bid = blockIdx.x;
  int n = bid >> 6, y = bid & 63;
  size_t rowbase = (size_t)bid * (64 * 128);
  for (int it = 0; it < 2; ++it) {
    int flat = (it * 1024 + tid) * 4;
    int px = flat >> 7, c = flat & 127;
    float4 v = *(const float4*)&z3[rowbase + flat];
    short tmp[4] = {f2bf(v.x), f2bf(v.y), f2bf(v.z), f2bf(v.w)};
    *(uint2*)&z3s[px * 136 + c] = *(uint2*)tmp;
  }
  __syncthreads();
  int w = tid >> 6, lane = tid & 63;
  int quad = lane >> 4, r16 = lane & 15;
  int wm = w & 3, wn = w >> 2;
  int strip = wm * 16;
  short8 a3[4];
#pragma unroll
  for (int kk = 0; kk < 4; ++kk)
    a3[kk] = *(const short8*)&z3s[(strip + r16) * 136 + kk * 32 + quad * 8];
  floatx4 zacc[2];
  zacc[0] = (floatx4){0.f, 0.f, 0.f, 0.f};
  zacc[1] = (floatx4){0.f, 0.f, 0.f, 0.f};
  for (int fc = 0; fc < 512; fc += 128) {
    __syncthreads();  // protect w1c/w2c/h1s from previous iteration readers
    const short* w1src = w1bf + fc * 136;
    const short* w2src = w2bf + (fc >> 7) * 17408;
    for (int i = tid; i < 2176; i += 1024) {
      *(short8*)&w1c[i * 8] = *(const short8*)&w1src[i * 8];
      *(short8*)&w2c[i * 8] = *(const short8*)&w2src[i * 8];
    }
    __syncthreads();
    // GEMM1: h1 chunk = z3 @ w1c^T, +bias, GELU -> h1s bf16
#pragma unroll
    for (int nt = 0; nt < 2; ++nt) {
      int f0 = wn * 32 + nt * 16;
      floatx4 acc = {0.f, 0.f, 0.f, 0.f};
#pragma unroll
      for (int kk = 0; kk < 4; ++kk) {
        short8 bfr = *(const short8*)&w1c[(f0 + r16) * 136 + kk * 32 + quad * 8];
        acc = MFMA16(a3[kk], bfr, acc);
      }
      float bb1 = b1[fc + f0 + r16];
#pragma unroll
      for (int r = 0; r < 4; ++r) {
        float hv = acc[r] + bb1;
        float ge = 0.5f * hv * (1.f + erff(hv * 0.70710678118f));
        h1s[(strip + quad * 4 + r) * 136 + f0 + r16] = f2bf(ge);
      }
    }
    __syncthreads();
    // GEMM2 partial: zacc += h1s @ w2c^T (local K=128)
    short8 ah[4];
#pragma unroll
    for (int kk = 0; kk < 4; ++kk)
      ah[kk] = *(const short8*)&h1s[(strip + r16) * 136 + kk * 32 + quad * 8];
#pragma unroll
    for (int nt = 0; nt < 2; ++nt) {
      int o0 = wn * 32 + nt * 16;
#pragma unroll
      for (int kk = 0; kk < 4; ++kk) {
        short8 bfr = *(const short8*)&w2c[(o0 + r16) * 136 + kk * 32 + quad * 8];
        zacc[nt] = MFMA16(ah[kk], bfr, zacc[nt]);
      }
    }
  }
  __syncthreads();  // done with w1c -> outt alias safe
#pragma unroll
  for (int nt = 0; nt < 2; ++nt) {
    int o0 = wn * 32 + nt * 16;
    float bb = b2[o0 + r16];
#pragma unroll
    for (int r = 0; r < 4; ++r) {
      int px = strip + quad * 4 + r;
      outt[(o0 + r16) * 65 + px] =
          zacc[nt][r] + bb + z2[rowbase + px * 128 + o0 + r16];
    }
  }
  __syncthreads();
  for (int it = 0; it < 8; ++it) {
    int flat = it * 1024 + tid;   // o*64 + px
    int o = flat >> 6, px = flat & 63;
    out[(((size_t)(n * 128 + o)) * 64 + y) * 64 + px] = outt[o * 65 + px];
  }
}

// ----------------------------------------------------------------
extern "C" void kernel_launch(void* const* d_in, const int* in_sizes, int n_in,
                              void* d_out, int out_size, void* d_ws, size_t ws_size,
                              hipStream_t stream) {
  const float* x        = (const float*)d_in[0];
  const float* qcoeff   = (const float*)d_in[1];
  const float* wq       = (const float*)d_in[2];
  const float* bq       = (const float*)d_in[3];
  const float* wk       = (const float*)d_in[4];
  const float* bk       = (const float*)d_in[5];
  const float* wv       = (const float*)d_in[6];
  const float* bv       = (const float*)d_in[7];
  const float* rel_bias = (const float*)d_in[8];
  const float* ln1_g    = (const float*)d_in[9];
  const float* ln1_b    = (const float*)d_in[10];
  const float* bil_w    = (const float*)d_in[11];
  const float* bil_b    = (const float*)d_in[12];
  const float* ln2_g    = (const float*)d_in[13];
  const float* ln2_b    = (const float*)d_in[14];
  const float* w1       = (const float*)d_in[15];
  const float* b1       = (const float*)d_in[16];
  const float* w2       = (const float*)d_in[17];
  const float* b2       = (const float*)d_in[18];
  float* out = (float*)d_out;

  float* ws = (float*)d_ws;
  float* x_nhwc = ws;            // [N,H,W,E]
  float* xn     = ws + 1 * SZ;   // LN1 output; aliased as z0 after QKV
  float* qb     = ws + 2 * SZ;   // aliased as z2 after attention
  float* kb     = ws + 3 * SZ;   // aliased as z3 after attention
  float* vb     = ws + 4 * SZ;
  short* bf     = (short*)(ws + 5 * SZ);
  short* tb     = bf;                    // [4][128][136] bf16
  short* w1bf   = bf + 4 * 17408;        // [512][136]
  short* w2bf   = w1bf + 512 * 136;      // [4][128][136]
  short* wqbf   = w2bf + 4 * 17408;      // [128][136]
  short* wkbf   = wqbf + 17408;
  short* wvbf   = wkbf + 17408;
  float* z0 = xn;
  float* z2 = qb;
  float* z3 = kb;

  k_prep<<<64, 256, 0, stream>>>(w1, w2, wq, wk, wv, w1bf, w2bf, wqbf, wkbf, wvbf);
  k_ln1<<<256, 256, 0, stream>>>(x, ln1_g, ln1_b, x_nhwc, xn);
  k_qkv<<<256, 1024, 0, stream>>>(xn, wqbf, wkbf, wvbf, bq, bk, bv, qb, kb, vb);
  k_t<<<64, 256, 0, stream>>>(bil_w, qcoeff, tb);
  k_attn<<<1024, 256, 0, stream>>>(qb, kb, vb, rel_bias, z0);
  k_bil<<<256, 1024, 0, stream>>>(z0, tb, bil_b, x_nhwc, ln2_g, ln2_b, z2, z3);
  k_ffn<<<256, 1024, 0, stream>>>(z3, z2, w1bf, b1, w2bf, b2, out);
}

// Round 6
// 174.308 us; speedup vs baseline: 1.1165x; 1.1165x over previous
//
#include <hip/hip_runtime.h>
#include <cmath>

#define EPS 1e-5f
#define SZ 2097152  // N*H*W*E = 4*64*64*128

typedef __attribute__((ext_vector_type(8))) short short8;   // 8 bf16 (4 VGPRs)
typedef __attribute__((ext_vector_type(4))) float floatx4;  // MFMA C/D frag

__device__ __forceinline__ float dot4(float4 a, float4 b) {
  return fmaf(a.x, b.x, fmaf(a.y, b.y, fmaf(a.z, b.z, a.w * b.w)));
}

__device__ __forceinline__ short f2bf(float f) {
  union { float f; unsigned u; } v; v.f = f;
  unsigned r = v.u + 0x7fff + ((v.u >> 16) & 1);  // RNE
  return (short)(r >> 16);
}

#define MFMA16(a, b, c) __builtin_amdgcn_mfma_f32_16x16x32_bf16(a, b, c, 0, 0, 0)

// ---------------------------------------------------------------- K0: weight prep (fp32 -> bf16, padded 136 rows)
// grid 64, block 256
__global__ __launch_bounds__(256) void k_prep(const float* __restrict__ w1,
    const float* __restrict__ w2, const float* __restrict__ wq,
    const float* __restrict__ wk, const float* __restrict__ wv,
    short* __restrict__ w1bf, short* __restrict__ w2bf,
    short* __restrict__ wqbf, short* __restrict__ wkbf, short* __restrict__ wvbf) {
  int tid0 = blockIdx.x * 256 + threadIdx.x;
  int stride = gridDim.x * 256;
  for (int i = tid0; i < 16384; i += stride) {
    int flat = i * 4; int f = flat >> 7, c = flat & 127;
    float4 v = *(const float4*)&w1[flat];
    short t4[4] = {f2bf(v.x), f2bf(v.y), f2bf(v.z), f2bf(v.w)};
    *(uint2*)&w1bf[f * 136 + c] = *(uint2*)t4;
  }
  for (int i = tid0; i < 16384; i += stride) {
    int flat = i * 4; int o = flat >> 9, j = flat & 511;
    int ck = j >> 7, jj = j & 127;
    float4 v = *(const float4*)&w2[flat];
    short t4[4] = {f2bf(v.x), f2bf(v.y), f2bf(v.z), f2bf(v.w)};
    *(uint2*)&w2bf[(ck * 128 + o) * 136 + jj] = *(uint2*)t4;
  }
  for (int i = tid0; i < 4096; i += stride) {
    int flat = i * 4; int o = flat >> 7, c = flat & 127;
    float4 a = *(const float4*)&wq[flat];
    float4 b = *(const float4*)&wk[flat];
    float4 cc = *(const float4*)&wv[flat];
    short ta[4] = {f2bf(a.x), f2bf(a.y), f2bf(a.z), f2bf(a.w)};
    short tb4[4] = {f2bf(b.x), f2bf(b.y), f2bf(b.z), f2bf(b.w)};
    short tc[4] = {f2bf(cc.x), f2bf(cc.y), f2bf(cc.z), f2bf(cc.w)};
    *(uint2*)&wqbf[o * 136 + c] = *(uint2*)ta;
    *(uint2*)&wkbf[o * 136 + c] = *(uint2*)tb4;
    *(uint2*)&wvbf[o * 136 + c] = *(uint2*)tc;
  }
}

// ---------------------------------------------------------------- K1: LN1 + transpose
// grid 256 = (n*64+y), block 256
__global__ __launch_bounds__(256) void k_ln1(const float* __restrict__ x,
    const float* __restrict__ g, const float* __restrict__ b,
    float* __restrict__ xnhwc, float* __restrict__ xn) {
  __shared__ float tile[128 * 65];
  __shared__ float mres[64], rres[64];
  int bid = blockIdx.x;
  int n = bid >> 6, y = bid & 63;
  const float* xb = x + (size_t)n * (128 * 64 * 64) + y * 64;
  int tid = threadIdx.x;
  for (int it = 0; it < 32; ++it) {
    int flat = it * 256 + tid;
    int c = flat >> 6, xp = flat & 63;
    tile[c * 65 + xp] = xb[(size_t)c * 4096 + xp];
  }
  __syncthreads();
  if (tid < 64) {
    float s = 0.f, sq = 0.f;
    for (int c = 0; c < 128; ++c) { float v = tile[c * 65 + tid]; s += v; sq += v * v; }
    float m = s * (1.f / 128.f);
    float var = sq * (1.f / 128.f) - m * m;
    mres[tid] = m;
    rres[tid] = rsqrtf(var + EPS);
  }
  __syncthreads();
  size_t rowbase = (size_t)bid * (64 * 128);
  for (int it = 0; it < 32; ++it) {
    int flat = it * 256 + tid;
    int c = flat & 127, px = flat >> 7;
    float v = tile[c * 65 + px];
    xnhwc[rowbase + flat] = v;
    xn[rowbase + flat] = (v - mres[px]) * rres[px] * g[c] + b[c];
  }
}

// ---------------------------------------------------------------- K2: QKV projection (MFMA bf16) -> bf16 outputs
// grid 256 = (n*64+y), block 1024 = 16 waves
// qbf/kbf: NHWC bf16 [n][y][x][128]; vtb: transposed bf16 [n*128+o][y*64+x]
__global__ __launch_bounds__(1024) void k_qkv(const float* __restrict__ xn,
    const short* __restrict__ wqbf, const short* __restrict__ wkbf,
    const short* __restrict__ wvbf, const float* __restrict__ bq,
    const float* __restrict__ bk, const float* __restrict__ bv,
    short* __restrict__ qbf, short* __restrict__ kbf, short* __restrict__ vtb) {
  __shared__ __align__(16) short xs[64 * 136];   // A: [px][c]
  __shared__ __align__(16) short ws[128 * 136];  // B: [o][c]
  int tid = threadIdx.x;
  int bid = blockIdx.x;
  int n = bid >> 6, y = bid & 63;
  size_t rowbase = (size_t)bid * (64 * 128);
  for (int it = 0; it < 2; ++it) {
    int flat = (it * 1024 + tid) * 4;
    int px = flat >> 7, c = flat & 127;
    float4 xv = *(const float4*)&xn[rowbase + flat];
    short tmp[4] = {f2bf(xv.x), f2bf(xv.y), f2bf(xv.z), f2bf(xv.w)};
    *(uint2*)&xs[px * 136 + c] = *(uint2*)tmp;
  }
  __syncthreads();
  int w = tid >> 6, lane = tid & 63;
  int quad = lane >> 4, r16 = lane & 15;
  int wm = w & 3, wn = w >> 2;
  int strip = wm * 16;
  short8 a[4];
#pragma unroll
  for (int kk = 0; kk < 4; ++kk)
    a[kk] = *(const short8*)&xs[(strip + r16) * 136 + kk * 32 + quad * 8];
  const short* wptr[3] = {wqbf, wkbf, wvbf};
  const float* bptr[3] = {bq, bk, bv};
  for (int m = 0; m < 3; ++m) {
    __syncthreads();
    const short* wp = wptr[m];
    for (int i = tid; i < 2176; i += 1024)
      *(short8*)&ws[i * 8] = *(const short8*)&wp[i * 8];
    __syncthreads();
    const float* bb = bptr[m];
#pragma unroll
    for (int nt = 0; nt < 2; ++nt) {
      int o0 = wn * 32 + nt * 16;
      floatx4 acc = {0.f, 0.f, 0.f, 0.f};
#pragma unroll
      for (int kk = 0; kk < 4; ++kk) {
        short8 bfr = *(const short8*)&ws[(o0 + r16) * 136 + kk * 32 + quad * 8];
        acc = MFMA16(a[kk], bfr, acc);
      }
      float bv2 = bb[o0 + r16];
      if (m < 2) {
        short* dst = (m == 0) ? qbf : kbf;
        size_t base = (size_t)bid * 8192;
#pragma unroll
        for (int r = 0; r < 4; ++r) {
          int px = strip + quad * 4 + r;
          dst[base + px * 128 + o0 + r16] = f2bf(acc[r] + bv2);
        }
      } else {
        short t4[4] = {f2bf(acc[0] + bv2), f2bf(acc[1] + bv2),
                       f2bf(acc[2] + bv2), f2bf(acc[3] + bv2)};
        *(uint2*)&vtb[(size_t)(n * 128 + o0 + r16) * 4096 + y * 64 + strip + quad * 4] =
            *(uint2*)t4;
      }
    }
  }
}

// ---------------------------------------------------------------- K3: local-window attention (MFMA, bf16 inputs)
// grid 1024 = ((n*64+y)*4+h), block 256 = 4 waves; wave w owns px strip [16w,16w+16)
__global__ __launch_bounds__(256) void k_attn(const short* __restrict__ qbf,
    const short* __restrict__ kbf, const short* __restrict__ vtb,
    const float* __restrict__ rel_bias, float* __restrict__ z0) {
  // LDS: KV union (Ks [7][80][40] 44800 B / Vt [7][32][72] 32256 B) | ssf [64][52] f32 | Ab 4x[16][72] | bias
  __shared__ __align__(16) char smem[44800 + 13312 + 9216 + 256];
  short* KV = (short*)smem;
  float* ssf = (float*)(smem + 44800);
  short* AbB = (short*)(smem + 44800 + 13312);
  float* bias = (float*)(smem + 44800 + 13312 + 9216);

  int bid = blockIdx.x;
  int h = bid & 3, y = (bid >> 2) & 63, n = bid >> 8;
  int tid = threadIdx.x;
  int w = tid >> 6, lane = tid & 63;
  int quad = lane >> 4, r16 = lane & 15;
  int strip = w * 16;
  short* Abw = AbB + w * (16 * 72);   // wave-private banded A strip, cols = gx [0,64)+pad

  // zero wave-private Ab strip (single-writer/single-reader within wave)
  {
    unsigned* ad = (unsigned*)Abw;
    for (int i = lane; i < 576; i += 64) ad[i] = 0u;
  }
  // Q fragment directly from bf16 global
  short8 qf = *(const short8*)&qbf[(size_t)n * 524288 +
                                   (size_t)(y * 64 + strip + r16) * 128 + h * 32 + quad * 8];
  // stage K rows: Ks[r][xx=gx+3][40]; OOB rows/cols left stale (cndmask at extraction)
  const short* kbp = kbf + (size_t)n * 524288 + h * 32;
  for (int u = tid; u < 1792; u += 256) {   // r*256 + gx*4 + d8
    int r = u >> 8, rest = u & 255;
    int gx = rest >> 2, d8 = rest & 3;
    int yy = y + r - 3;
    if ((unsigned)yy < 64u) {
      uint4 v = *(const uint4*)&kbp[(size_t)(yy * 64 + gx) * 128 + d8 * 8];
      *(uint4*)&KV[(r * 80 + gx + 3) * 40 + d8 * 8] = v;
    }
  }
  if (tid < 49) bias[tid] = rel_bias[h * 49 + tid];
  __syncthreads();

  // QK^T: 2 N-tiles intersecting this strip's band (xx coords)
  bool yyok[7];
#pragma unroll
  for (int r = 0; r < 7; ++r) yyok[r] = (unsigned)(y + r - 3) < 64u;
#pragma unroll
  for (int r = 0; r < 7; ++r) {
#pragma unroll
    for (int t = 0; t < 2; ++t) {
      int xxc = (w + t) * 16 + r16;
      short8 bf = *(const short8*)&KV[(r * 80 + xxc) * 40 + quad * 8];
      floatx4 c = MFMA16(qf, bf, ((floatx4){0.f, 0.f, 0.f, 0.f}));
#pragma unroll
      for (int rr = 0; rr < 4; ++rr) {
        int px = strip + quad * 4 + rr;
        int dx = xxc - px;
        if ((unsigned)dx < 7u) {
          int gxv = xxc - 3;
          float val = (yyok[r] && (unsigned)gxv < 64u) ? c[rr] : 0.f;
          ssf[px * 52 + r * 7 + dx] = val + bias[r * 7 + dx];
        }
      }
    }
  }
  __syncthreads();   // all waves done reading Ks
  // stage V^T (overwrites Ks): Vt[r][d][72], cols = gx, contiguous copies from vtb
  const short* vbp = vtb + (size_t)(n * 128 + h * 32) * 4096;
  for (int u = tid; u < 1792; u += 256) {   // r*256 + d*8 + g
    int r = u >> 8, rest = u & 255;
    int d = rest >> 3, g = rest & 7;
    int yy = y + r - 3;
    uint4 v = {0u, 0u, 0u, 0u};
    if ((unsigned)yy < 64u)
      v = *(const uint4*)&vbp[(size_t)d * 4096 + yy * 64 + g * 8];
    *(uint4*)&KV[(r * 32 + d) * 72 + g * 8] = v;   // zero rows for OOB yy
  }
  // softmax over 49 positions (ssf rows are wave-local)
  {
    int px = tid >> 2, sub = tid & 3;
    int p0 = sub * 12, cnt = (sub == 3) ? 13 : 12;
    float sv[13];
    float mx = -1e30f;
    for (int pi = 0; pi < cnt; ++pi) { sv[pi] = ssf[px * 52 + p0 + pi]; mx = fmaxf(mx, sv[pi]); }
    mx = fmaxf(mx, __shfl_xor(mx, 1));
    mx = fmaxf(mx, __shfl_xor(mx, 2));
    float sum = 0.f;
    for (int pi = 0; pi < cnt; ++pi) { float e = __expf(sv[pi] - mx); sv[pi] = e; sum += e; }
    sum += __shfl_xor(sum, 1);
    sum += __shfl_xor(sum, 2);
    float inv = 1.f / sum;
    for (int pi = 0; pi < cnt; ++pi) ssf[px * 52 + p0 + pi] = sv[pi] * inv;
  }
  __syncthreads();   // Vt staged (block-cyclic) -> visible to all waves
  // PV: wave-private banded A (gx coords); OOB-gx attn cols dropped (V=0 in reference)
  floatx4 oacc[2] = {(floatx4){0.f, 0.f, 0.f, 0.f}, (floatx4){0.f, 0.f, 0.f, 0.f}};
  int lrow = lane >> 2, sub = lane & 3;
  int pxg = strip + lrow;
  int kk0 = (w == 3) ? 1 : 0;
  int kk1 = (w == 0) ? 0 : 1;
  for (int r = 0; r < 7; ++r) {
    int c0 = pxg + sub - 3;            // dx = sub
    if ((unsigned)c0 < 64u) Abw[lrow * 72 + c0] = f2bf(ssf[pxg * 52 + r * 7 + sub]);
    int c1 = pxg + sub + 1;            // dx = sub+4
    if (sub < 3 && (unsigned)c1 < 64u)
      Abw[lrow * 72 + c1] = f2bf(ssf[pxg * 52 + r * 7 + sub + 4]);
    for (int kk = kk0; kk <= kk1; ++kk) {
      short8 af = *(const short8*)&Abw[r16 * 72 + kk * 32 + quad * 8];
#pragma unroll
      for (int nt = 0; nt < 2; ++nt) {
        short8 vf = *(const short8*)&KV[(r * 32 + nt * 16 + r16) * 72 + kk * 32 + quad * 8];
        oacc[nt] = MFMA16(af, vf, oacc[nt]);
      }
    }
  }
  // epilogue: C[px][d] -> z0 (fp32 NHWC)
  float* zrow = z0 + (size_t)n * 524288 + (size_t)y * 64 * 128 + h * 32;
#pragma unroll
  for (int nt = 0; nt < 2; ++nt)
#pragma unroll
    for (int rr = 0; rr < 4; ++rr) {
      int px = strip + quad * 4 + rr;
      zrow[px * 128 + nt * 16 + r16] = oacc[nt][rr];
    }
}

// ---------------------------------------------------------------- K4: t = bil_w . qcoeff -> bf16 (padded 136)
// grid 64, block 256
__global__ __launch_bounds__(256) void k_t(const float* __restrict__ bil_w,
    const float* __restrict__ qcoeff, short* __restrict__ t) {
  __shared__ float qs[4 * 64];
  int tid = threadIdx.x;
  qs[tid] = qcoeff[tid];
  __syncthreads();
  int flat = blockIdx.x * 256 + tid;          // o*128 + i
  const float* wrow = bil_w + (size_t)flat * 64;
  float acc[4] = {0.f, 0.f, 0.f, 0.f};
  for (int qq = 0; qq < 64; qq += 4) {
    float4 w4 = *(const float4*)&wrow[qq];
#pragma unroll
    for (int nn = 0; nn < 4; ++nn) {
      const float* qc = &qs[nn * 64 + qq];
      acc[nn] = fmaf(w4.x, qc[0], fmaf(w4.y, qc[1], fmaf(w4.z, qc[2], fmaf(w4.w, qc[3], acc[nn]))));
    }
  }
  int o = flat >> 7, i = flat & 127;
#pragma unroll
  for (int nn = 0; nn < 4; ++nn) t[nn * 17408 + o * 136 + i] = f2bf(acc[nn]);
}

// ---------------------------------------------------------------- K5: bilinear (MFMA) + residual + LN2
// grid 256 = (n*64+y), block 1024 = 16 waves
__global__ __launch_bounds__(1024) void k_bil(const float* __restrict__ z0,
    const short* __restrict__ tb, const float* __restrict__ bil_b,
    const float* __restrict__ xnhwc, const float* __restrict__ g2,
    const float* __restrict__ b2ln, float* __restrict__ z2,
    float* __restrict__ z3) {
  __shared__ __align__(16) short zs[64 * 136];
  __shared__ __align__(16) short ts[128 * 136];
  __shared__ __align__(16) float z2s[64 * 132];
  int tid = threadIdx.x;
  int bid = blockIdx.x;
  int n = bid >> 6;
  size_t rowbase = (size_t)bid * (64 * 128);
  for (int it = 0; it < 2; ++it) {
    int flat = (it * 1024 + tid) * 4;
    int px = flat >> 7, c = flat & 127;
    float4 v = *(const float4*)&z0[rowbase + flat];
    short tmp[4] = {f2bf(v.x), f2bf(v.y), f2bf(v.z), f2bf(v.w)};
    *(uint2*)&zs[px * 136 + c] = *(uint2*)tmp;
  }
  const short* tn = tb + (size_t)n * 17408;
  for (int i = tid; i < 2176; i += 1024)
    *(short8*)&ts[i * 8] = *(const short8*)&tn[i * 8];
  __syncthreads();
  int w = tid >> 6, lane = tid & 63;
  int quad = lane >> 4, r16 = lane & 15;
  int wm = w & 3, wn = w >> 2;
  int strip = wm * 16;
  short8 a[4];
#pragma unroll
  for (int kk = 0; kk < 4; ++kk)
    a[kk] = *(const short8*)&zs[(strip + r16) * 136 + kk * 32 + quad * 8];
#pragma unroll
  for (int nt = 0; nt < 2; ++nt) {
    int o0 = wn * 32 + nt * 16;
    floatx4 acc = {0.f, 0.f, 0.f, 0.f};
#pragma unroll
    for (int kk = 0; kk < 4; ++kk) {
      short8 bfr = *(const short8*)&ts[(o0 + r16) * 136 + kk * 32 + quad * 8];
      acc = MFMA16(a[kk], bfr, acc);
    }
    float bb = bil_b[o0 + r16];
#pragma unroll
    for (int r = 0; r < 4; ++r) {
      int px = strip + quad * 4 + r;
      z2s[px * 132 + o0 + r16] = acc[r] + bb + xnhwc[rowbase + px * 128 + o0 + r16];
    }
  }
  __syncthreads();
  {
    int px = tid >> 4, cl = tid & 15;
    float4 v0 = *(const float4*)&z2s[px * 132 + cl * 8];
    float4 v1 = *(const float4*)&z2s[px * 132 + cl * 8 + 4];
    float s = v0.x + v0.y + v0.z + v0.w + v1.x + v1.y + v1.z + v1.w;
    float sq = dot4(v0, v0) + dot4(v1, v1);
    s += __shfl_xor(s, 1);  sq += __shfl_xor(sq, 1);
    s += __shfl_xor(s, 2);  sq += __shfl_xor(sq, 2);
    s += __shfl_xor(s, 4);  sq += __shfl_xor(sq, 4);
    s += __shfl_xor(s, 8);  sq += __shfl_xor(sq, 8);
    float m = s * (1.f / 128.f);
    float var = sq * (1.f / 128.f) - m * m;
    float rr = rsqrtf(var + EPS);
    int c0 = cl * 8;
    float o0v[8];
#pragma unroll
    for (int j = 0; j < 8; ++j) o0v[j] = (j < 4) ? (&v0.x)[j] : (&v1.x)[j - 4];
    float* z2p = &z2[rowbase + px * 128 + c0];
    float* z3p = &z3[rowbase + px * 128 + c0];
#pragma unroll
    for (int j = 0; j < 8; ++j) {
      z2p[j] = o0v[j];
      z3p[j] = (o0v[j] - m) * rr * g2[c0 + j] + b2ln[c0 + j];
    }
  }
}

// ---------------------------------------------------------------- K6: FFN (MFMA) + residual + NCHW
// grid 256 = (n*64+y), block 1024 = 16 waves; f-chunks of 128
__global__ __launch_bounds__(1024) void k_ffn(const float* __restrict__ z3,
    const float* __restrict__ z2, const short* __restrict__ w1bf,
    const float* __restrict__ b1, const short* __restrict__ w2bf,
    const float* __restrict__ b2, float* __restrict__ out) {
  __shared__ __align__(16) char smem[17408 + 34816 + 17408 + 34816];
  short* z3s = (short*)smem;
  short* w1c = (short*)(smem + 17408);
  short* h1s = (short*)(smem + 17408 + 34816);
  short* w2c = (short*)(smem + 17408 + 34816 + 17408);
  float* outt = (float*)(smem + 17408);
  int tid = threadIdx.x;
  int bid = blockIdx.x;
  int n = bid >> 6, y = bid & 63;
  size_t rowbase = (size_t)bid * (64 * 128);
  for (int it = 0; it < 2; ++it) {
    int flat = (it * 1024 + tid) * 4;
    int px = flat >> 7, c = flat & 127;
    float4 v = *(const float4*)&z3[rowbase + flat];
    short tmp[4] = {f2bf(v.x), f2bf(v.y), f2bf(v.z), f2bf(v.w)};
    *(uint2*)&z3s[px * 136 + c] = *(uint2*)tmp;
  }
  __syncthreads();
  int w = tid >> 6, lane = tid & 63;
  int quad = lane >> 4, r16 = lane & 15;
  int wm = w & 3, wn = w >> 2;
  int strip = wm * 16;
  short8 a3[4];
#pragma unroll
  for (int kk = 0; kk < 4; ++kk)
    a3[kk] = *(const short8*)&z3s[(strip + r16) * 136 + kk * 32 + quad * 8];
  floatx4 zacc[2];
  zacc[0] = (floatx4){0.f, 0.f, 0.f, 0.f};
  zacc[1] = (floatx4){0.f, 0.f, 0.f, 0.f};
  for (int fc = 0; fc < 512; fc += 128) {
    __syncthreads();
    const short* w1src = w1bf + fc * 136;
    const short* w2src = w2bf + (fc >> 7) * 17408;
    for (int i = tid; i < 2176; i += 1024) {
      *(short8*)&w1c[i * 8] = *(const short8*)&w1src[i * 8];
      *(short8*)&w2c[i * 8] = *(const short8*)&w2src[i * 8];
    }
    __syncthreads();
#pragma unroll
    for (int nt = 0; nt < 2; ++nt) {
      int f0 = wn * 32 + nt * 16;
      floatx4 acc = {0.f, 0.f, 0.f, 0.f};
#pragma unroll
      for (int kk = 0; kk < 4; ++kk) {
        short8 bfr = *(const short8*)&w1c[(f0 + r16) * 136 + kk * 32 + quad * 8];
        acc = MFMA16(a3[kk], bfr, acc);
      }
      float bb1 = b1[fc + f0 + r16];
#pragma unroll
      for (int r = 0; r < 4; ++r) {
        float hv = acc[r] + bb1;
        float ge = 0.5f * hv * (1.f + erff(hv * 0.70710678118f));
        h1s[(strip + quad * 4 + r) * 136 + f0 + r16] = f2bf(ge);
      }
    }
    __syncthreads();
    short8 ah[4];
#pragma unroll
    for (int kk = 0; kk < 4; ++kk)
      ah[kk] = *(const short8*)&h1s[(strip + r16) * 136 + kk * 32 + quad * 8];
#pragma unroll
    for (int nt = 0; nt < 2; ++nt) {
      int o0 = wn * 32 + nt * 16;
#pragma unroll
      for (int kk = 0; kk < 4; ++kk) {
        short8 bfr = *(const short8*)&w2c[(o0 + r16) * 136 + kk * 32 + quad * 8];
        zacc[nt] = MFMA16(ah[kk], bfr, zacc[nt]);
      }
    }
  }
  __syncthreads();
#pragma unroll
  for (int nt = 0; nt < 2; ++nt) {
    int o0 = wn * 32 + nt * 16;
    float bb = b2[o0 + r16];
#pragma unroll
    for (int r = 0; r < 4; ++r) {
      int px = strip + quad * 4 + r;
      outt[(o0 + r16) * 65 + px] =
          zacc[nt][r] + bb + z2[rowbase + px * 128 + o0 + r16];
    }
  }
  __syncthreads();
  for (int it = 0; it < 8; ++it) {
    int flat = it * 1024 + tid;
    int o = flat >> 6, px = flat & 63;
    out[(((size_t)(n * 128 + o)) * 64 + y) * 64 + px] = outt[o * 65 + px];
  }
}

// ----------------------------------------------------------------
extern "C" void kernel_launch(void* const* d_in, const int* in_sizes, int n_in,
                              void* d_out, int out_size, void* d_ws, size_t ws_size,
                              hipStream_t stream) {
  const float* x        = (const float*)d_in[0];
  const float* qcoeff   = (const float*)d_in[1];
  const float* wq       = (const float*)d_in[2];
  const float* bq       = (const float*)d_in[3];
  const float* wk       = (const float*)d_in[4];
  const float* bk       = (const float*)d_in[5];
  const float* wv       = (const float*)d_in[6];
  const float* bv       = (const float*)d_in[7];
  const float* rel_bias = (const float*)d_in[8];
  const float* ln1_g    = (const float*)d_in[9];
  const float* ln1_b    = (const float*)d_in[10];
  const float* bil_w    = (const float*)d_in[11];
  const float* bil_b    = (const float*)d_in[12];
  const float* ln2_g    = (const float*)d_in[13];
  const float* ln2_b    = (const float*)d_in[14];
  const float* w1       = (const float*)d_in[15];
  const float* b1       = (const float*)d_in[16];
  const float* w2       = (const float*)d_in[17];
  const float* b2       = (const float*)d_in[18];
  float* out = (float*)d_out;

  float* ws = (float*)d_ws;
  float* x_nhwc = ws;                    // A: [N,H,W,E] fp32, 8MB
  float* xn     = ws + 1 * SZ;           // B: LN1 out; aliased as z0 after QKV
  // C region [2SZ, 4SZ): qbf/kbf/vtb bf16 (live k_qkv->k_attn), then z2/z3 fp32
  short* qbf = (short*)(ws + 2 * SZ);    // 2M shorts
  short* kbf = qbf + SZ;                 // 2M shorts
  short* vtb = kbf + SZ;                 // 2M shorts, [n*128+o][4096]
  float* z2 = ws + 2 * SZ;               // overlays qbf+kbf (dead after k_attn)
  float* z3 = ws + 3 * SZ;               // overlays vtb+pad
  // D region: bf16 weights
  short* bf     = (short*)(ws + 4 * SZ);
  short* tb     = bf;                    // [4][128][136]
  short* w1bf   = bf + 4 * 17408;        // [512][136]
  short* w2bf   = w1bf + 512 * 136;      // [4][128][136]
  short* wqbf   = w2bf + 4 * 17408;      // [128][136]
  short* wkbf   = wqbf + 17408;
  short* wvbf   = wkbf + 17408;
  float* z0 = xn;

  k_prep<<<64, 256, 0, stream>>>(w1, w2, wq, wk, wv, w1bf, w2bf, wqbf, wkbf, wvbf);
  k_ln1<<<256, 256, 0, stream>>>(x, ln1_g, ln1_b, x_nhwc, xn);
  k_qkv<<<256, 1024, 0, stream>>>(xn, wqbf, wkbf, wvbf, bq, bk, bv, qbf, kbf, vtb);
  k_t<<<64, 256, 0, stream>>>(bil_w, qcoeff, tb);
  k_attn<<<1024, 256, 0, stream>>>(qbf, kbf, vtb, rel_bias, z0);
  k_bil<<<256, 1024, 0, stream>>>(z0, tb, bil_b, x_nhwc, ln2_g, ln2_b, z2, z3);
  k_ffn<<<256, 1024, 0, stream>>>(z3, z2, w1bf, b1, w2bf, b2, out);
}

// Round 7
// 151.715 us; speedup vs baseline: 1.2828x; 1.1489x over previous
//
#include <hip/hip_runtime.h>
#include <cmath>

#define EPS 1e-5f
#define SZ 2097152  // N*H*W*E = 4*64*64*128

typedef __attribute__((ext_vector_type(8))) short short8;   // 8 bf16 (4 VGPRs)
typedef __attribute__((ext_vector_type(4))) float floatx4;  // MFMA C/D frag

__device__ __forceinline__ float dot4(float4 a, float4 b) {
  return fmaf(a.x, b.x, fmaf(a.y, b.y, fmaf(a.z, b.z, a.w * b.w)));
}

__device__ __forceinline__ short f2bf(float f) {
  union { float f; unsigned u; } v; v.f = f;
  unsigned r = v.u + 0x7fff + ((v.u >> 16) & 1);  // RNE
  return (short)(r >> 16);
}

#define MFMA16(a, b, c) __builtin_amdgcn_mfma_f32_16x16x32_bf16(a, b, c, 0, 0, 0)

// ---------------------------------------------------------------- K0: prep (weights fp32->bf16 padded; t = bil_w.qcoeff)
// grid 64, block 256 (16384 threads total)
__global__ __launch_bounds__(256) void k_prep(const float* __restrict__ w1,
    const float* __restrict__ w2, const float* __restrict__ wq,
    const float* __restrict__ wk, const float* __restrict__ wv,
    const float* __restrict__ bil_w, const float* __restrict__ qcoeff,
    short* __restrict__ w1bf, short* __restrict__ w2bf,
    short* __restrict__ wqbf, short* __restrict__ wkbf, short* __restrict__ wvbf,
    short* __restrict__ tb) {
  __shared__ float qs[256];
  int tid = threadIdx.x;
  qs[tid] = qcoeff[tid];
  __syncthreads();
  int tid0 = blockIdx.x * 256 + tid;
  int stride = gridDim.x * 256;
  // w1 [512f][128c] -> [512][136]
  for (int i = tid0; i < 16384; i += stride) {
    int flat = i * 4; int f = flat >> 7, c = flat & 127;
    float4 v = *(const float4*)&w1[flat];
    short t4[4] = {f2bf(v.x), f2bf(v.y), f2bf(v.z), f2bf(v.w)};
    *(uint2*)&w1bf[f * 136 + c] = *(uint2*)t4;
  }
  // w2 [128o][512j] -> 4 chunks of [128o][136]
  for (int i = tid0; i < 16384; i += stride) {
    int flat = i * 4; int o = flat >> 9, j = flat & 511;
    int ck = j >> 7, jj = j & 127;
    float4 v = *(const float4*)&w2[flat];
    short t4[4] = {f2bf(v.x), f2bf(v.y), f2bf(v.z), f2bf(v.w)};
    *(uint2*)&w2bf[(ck * 128 + o) * 136 + jj] = *(uint2*)t4;
  }
  // wq/wk/wv [128o][128c] -> [128][136]
  for (int i = tid0; i < 4096; i += stride) {
    int flat = i * 4; int o = flat >> 7, c = flat & 127;
    float4 a = *(const float4*)&wq[flat];
    float4 b = *(const float4*)&wk[flat];
    float4 cc = *(const float4*)&wv[flat];
    short ta[4] = {f2bf(a.x), f2bf(a.y), f2bf(a.z), f2bf(a.w)};
    short tb4[4] = {f2bf(b.x), f2bf(b.y), f2bf(b.z), f2bf(b.w)};
    short tc[4] = {f2bf(cc.x), f2bf(cc.y), f2bf(cc.z), f2bf(cc.w)};
    *(uint2*)&wqbf[o * 136 + c] = *(uint2*)ta;
    *(uint2*)&wkbf[o * 136 + c] = *(uint2*)tb4;
    *(uint2*)&wvbf[o * 136 + c] = *(uint2*)tc;
  }
  // t[n][o][i] = sum_q bil_w[o][i][q] * qcoeff[n][q]  -> bf16 padded 136
  {
    int flat = tid0;                          // o*128 + i, exactly 16384 threads
    const float* wrow = bil_w + (size_t)flat * 64;
    float acc[4] = {0.f, 0.f, 0.f, 0.f};
    for (int qq = 0; qq < 64; qq += 4) {
      float4 w4 = *(const float4*)&wrow[qq];
#pragma unroll
      for (int nn = 0; nn < 4; ++nn) {
        const float* qc = &qs[nn * 64 + qq];
        acc[nn] = fmaf(w4.x, qc[0], fmaf(w4.y, qc[1], fmaf(w4.z, qc[2], fmaf(w4.w, qc[3], acc[nn]))));
      }
    }
    int o = flat >> 7, i = flat & 127;
#pragma unroll
    for (int nn = 0; nn < 4; ++nn) tb[nn * 17408 + o * 136 + i] = f2bf(acc[nn]);
  }
}

// ---------------------------------------------------------------- K1: LN1 + transpose + QKV (MFMA) -> bf16 outputs
// grid 256 = (n*64+y), block 1024 = 16 waves
__global__ __launch_bounds__(1024) void k_qkvln(const float* __restrict__ x,
    const float* __restrict__ g, const float* __restrict__ b,
    const short* __restrict__ wqbf, const short* __restrict__ wkbf,
    const short* __restrict__ wvbf, const float* __restrict__ bq,
    const float* __restrict__ bk, const float* __restrict__ bv,
    float* __restrict__ xnhwc, short* __restrict__ qbf,
    short* __restrict__ kbf, short* __restrict__ vtb) {
  __shared__ float tile[128 * 65];               // x NCHW tile [c][xp]
  __shared__ float mres[64], rres[64];
  __shared__ __align__(16) short xs[64 * 136];   // A: [px][c] bf16
  __shared__ __align__(16) short ws[128 * 136];  // B: [o][c] bf16
  int tid = threadIdx.x;
  int bid = blockIdx.x;
  int n = bid >> 6, y = bid & 63;
  const float* xb = x + (size_t)n * (128 * 4096) + y * 64;
  for (int it = 0; it < 8; ++it) {
    int flat = it * 1024 + tid;                  // c*64 + xp
    int c = flat >> 6, xp = flat & 63;
    tile[c * 65 + xp] = xb[(size_t)c * 4096 + xp];
  }
  __syncthreads();
  // LN stats: 16 lanes per px
  {
    int px = tid >> 4, cl = tid & 15;
    float s = 0.f, sq = 0.f;
#pragma unroll
    for (int j = 0; j < 8; ++j) {
      float v = tile[(cl * 8 + j) * 65 + px];
      s += v; sq += v * v;
    }
    s += __shfl_xor(s, 1);  sq += __shfl_xor(sq, 1);
    s += __shfl_xor(s, 2);  sq += __shfl_xor(sq, 2);
    s += __shfl_xor(s, 4);  sq += __shfl_xor(sq, 4);
    s += __shfl_xor(s, 8);  sq += __shfl_xor(sq, 8);
    if (cl == 0) {
      float m = s * (1.f / 128.f);
      float var = sq * (1.f / 128.f) - m * m;
      mres[px] = m;
      rres[px] = rsqrtf(var + EPS);
    }
  }
  __syncthreads();
  size_t rowbase = (size_t)bid * 8192;
  for (int it = 0; it < 8; ++it) {
    int flat = it * 1024 + tid;                  // px*128 + c
    int c = flat & 127, px = flat >> 7;
    float v = tile[c * 65 + px];
    xnhwc[rowbase + flat] = v;
    xs[px * 136 + c] = f2bf((v - mres[px]) * rres[px] * g[c] + b[c]);
  }
  __syncthreads();
  int w = tid >> 6, lane = tid & 63;
  int quad = lane >> 4, r16 = lane & 15;
  int wm = w & 3, wn = w >> 2;
  int strip = wm * 16;
  short8 a[4];
#pragma unroll
  for (int kk = 0; kk < 4; ++kk)
    a[kk] = *(const short8*)&xs[(strip + r16) * 136 + kk * 32 + quad * 8];
  const short* wptr[3] = {wqbf, wkbf, wvbf};
  const float* bptr[3] = {bq, bk, bv};
  for (int m = 0; m < 3; ++m) {
    __syncthreads();
    const short* wp = wptr[m];
    for (int i = tid; i < 2176; i += 1024)
      *(short8*)&ws[i * 8] = *(const short8*)&wp[i * 8];
    __syncthreads();
    const float* bb = bptr[m];
#pragma unroll
    for (int nt = 0; nt < 2; ++nt) {
      int o0 = wn * 32 + nt * 16;
      floatx4 acc = {0.f, 0.f, 0.f, 0.f};
#pragma unroll
      for (int kk = 0; kk < 4; ++kk) {
        short8 bfr = *(const short8*)&ws[(o0 + r16) * 136 + kk * 32 + quad * 8];
        acc = MFMA16(a[kk], bfr, acc);
      }
      float bv2 = bb[o0 + r16];
      if (m < 2) {
        short* dst = (m == 0) ? qbf : kbf;
#pragma unroll
        for (int r = 0; r < 4; ++r) {
          int px = strip + quad * 4 + r;
          dst[rowbase + px * 128 + o0 + r16] = f2bf(acc[r] + bv2);
        }
      } else {
        short t4[4] = {f2bf(acc[0] + bv2), f2bf(acc[1] + bv2),
                       f2bf(acc[2] + bv2), f2bf(acc[3] + bv2)};
        *(uint2*)&vtb[(size_t)(n * 128 + o0 + r16) * 4096 + y * 64 + strip + quad * 4] =
            *(uint2*)t4;
      }
    }
  }
}

// ---------------------------------------------------------------- K2: attention — direct-global K/V frags, zero barriers
// grid 1024 = ((n*64+y)*4+h), block 256 = 4 waves; wave w owns px strip [16w,16w+16)
__global__ __launch_bounds__(256) void k_attn(const short* __restrict__ qbf,
    const short* __restrict__ kbf, const short* __restrict__ vtb,
    const float* __restrict__ rel_bias, float* __restrict__ z0) {
  __shared__ float ssf[4][16 * 50];               // per-wave scores/attn
  __shared__ __align__(16) short AbB[4][16 * 68]; // per-wave banded A (cols = gx)
  __shared__ float biasS[4][52];                  // per-wave bias copy
  int bid = blockIdx.x;
  int h = bid & 3, y = (bid >> 2) & 63, n = bid >> 8;
  int tid = threadIdx.x;
  int w = tid >> 6, lane = tid & 63;
  int quad = lane >> 4, r16 = lane & 15;
  int strip = w * 16;
  float* ssfw = ssf[w];
  short* Abw = AbB[w];
  float* biasw = biasS[w];
  // zero wave-private Ab (single wave writer/reader: in-order LDS, no barrier)
  {
    unsigned* ad = (unsigned*)Abw;
    for (int i = lane; i < 544; i += 64) ad[i] = 0u;
  }
  if (lane < 49) biasw[lane] = rel_bias[h * 49 + lane];
  // Q fragment from bf16 global
  const short* qrow = qbf + (size_t)n * 524288 + (size_t)y * 64 * 128 + h * 32;
  short8 qf = *(const short8*)&qrow[(strip + r16) * 128 + quad * 8];
  // QK^T: B-frags direct from kbf (NHWC, d contiguous); clamp addr, mask OOB
  const short* kbp = kbf + (size_t)n * 524288 + h * 32;
#pragma unroll
  for (int r = 0; r < 7; ++r) {
    int yy = y + r - 3;
    bool yok = (unsigned)yy < 64u;
    int yyc = min(max(yy, 0), 63);
#pragma unroll
    for (int t = 0; t < 2; ++t) {
      int xxc = (w + t) * 16 + r16;               // score column (gx = xxc-3)
      int gx = xxc - 3;
      bool ok = yok && ((unsigned)gx < 64u);
      int gxc = min(max(gx, 0), 63);
      short8 bf = *(const short8*)&kbp[(size_t)(yyc * 64 + gxc) * 128 + quad * 8];
      floatx4 c = MFMA16(qf, bf, ((floatx4){0.f, 0.f, 0.f, 0.f}));
#pragma unroll
      for (int rr = 0; rr < 4; ++rr) {
        int lrow = quad * 4 + rr;                 // local px row
        int dx = xxc - (strip + lrow);
        if ((unsigned)dx < 7u) {
          float val = ok ? c[rr] : 0.f;           // reference zero-pads K
          ssfw[lrow * 50 + r * 7 + dx] = val + biasw[r * 7 + dx];
        }
      }
    }
  }
  // softmax over 49 positions (wave-local rows, 4 lanes/row)
  {
    int lrow = lane >> 2, sub = lane & 3;
    int p0 = sub * 12, cnt = (sub == 3) ? 13 : 12;
    float sv[13];
    float mx = -1e30f;
    for (int pi = 0; pi < cnt; ++pi) { sv[pi] = ssfw[lrow * 50 + p0 + pi]; mx = fmaxf(mx, sv[pi]); }
    mx = fmaxf(mx, __shfl_xor(mx, 1));
    mx = fmaxf(mx, __shfl_xor(mx, 2));
    float sum = 0.f;
    for (int pi = 0; pi < cnt; ++pi) { float e = __expf(sv[pi] - mx); sv[pi] = e; sum += e; }
    sum += __shfl_xor(sum, 1);
    sum += __shfl_xor(sum, 2);
    float inv = 1.f / sum;
    for (int pi = 0; pi < cnt; ++pi) ssfw[lrow * 50 + p0 + pi] = sv[pi] * inv;
  }
  // PV: banded A in wave-private LDS; V B-frags direct from vtb (gx contiguous)
  floatx4 oacc[2] = {(floatx4){0.f, 0.f, 0.f, 0.f}, (floatx4){0.f, 0.f, 0.f, 0.f}};
  int kk0 = (w == 3) ? 1 : 0;
  int kk1 = (w == 0) ? 0 : 1;
  int lrow = lane >> 2, sub = lane & 3;
  int pxg = strip + lrow;
  const short* vbp = vtb + (size_t)(n * 128 + h * 32) * 4096;
  for (int r = 0; r < 7; ++r) {
    int yy = y + r - 3;
    bool yok = (unsigned)yy < 64u;
    int yyc = min(max(yy, 0), 63);
    int c0 = pxg + sub - 3;                       // dx = sub
    if ((unsigned)c0 < 64u) Abw[lrow * 68 + c0] = f2bf(ssfw[lrow * 50 + r * 7 + sub]);
    int c1 = pxg + sub + 1;                       // dx = sub+4
    if (sub < 3 && (unsigned)c1 < 64u)
      Abw[lrow * 68 + c1] = f2bf(ssfw[lrow * 50 + r * 7 + sub + 4]);
    for (int kk = kk0; kk <= kk1; ++kk) {
      short8 af = *(const short8*)&Abw[r16 * 68 + kk * 32 + quad * 8];
#pragma unroll
      for (int nt = 0; nt < 2; ++nt) {
        short8 vf = *(const short8*)&vbp[(size_t)(nt * 16 + r16) * 4096 + yyc * 64 + kk * 32 + quad * 8];
        if (!yok) vf = (short8){0, 0, 0, 0, 0, 0, 0, 0};  // reference zero-pads V
        oacc[nt] = MFMA16(af, vf, oacc[nt]);
      }
    }
  }
  // epilogue: C[px][d] -> z0 (fp32 NHWC)
  float* zrow = z0 + (size_t)n * 524288 + (size_t)y * 64 * 128 + h * 32;
#pragma unroll
  for (int nt = 0; nt < 2; ++nt)
#pragma unroll
    for (int rr = 0; rr < 4; ++rr) {
      int px = strip + quad * 4 + rr;
      zrow[px * 128 + nt * 16 + r16] = oacc[nt][rr];
    }
}

// ---------------------------------------------------------------- K3: bilinear + residual + LN2 + FFN + NCHW out
// grid 256 = (n*64+y), block 1024 = 16 waves
__global__ __launch_bounds__(1024) void k_tail(const float* __restrict__ z0,
    const short* __restrict__ tb, const float* __restrict__ bil_b,
    const float* __restrict__ xnhwc, const float* __restrict__ g2,
    const float* __restrict__ b2ln, const short* __restrict__ w1bf,
    const float* __restrict__ b1, const short* __restrict__ w2bf,
    const float* __restrict__ b2, float* __restrict__ out) {
  __shared__ __align__(16) char smem[34816 + 34816 + 17408 + 17408 + 33792];
  short* R1s = (short*)smem;                      // ts (phase A) / w1c (phase B); outt aliases
  short* w2c = (short*)(smem + 34816);
  short* z3s = (short*)(smem + 69632);            // zs (phase A) / z3s (phase B)
  short* h1s = (short*)(smem + 87040);
  float* z2s = (float*)(smem + 104448);           // [64][132] fp32, persistent
  float* outt = (float*)smem;                     // [128][65] fp32 epilogue
  int tid = threadIdx.x;
  int bid = blockIdx.x;
  int n = bid >> 6, y = bid & 63;
  size_t rowbase = (size_t)bid * 8192;
  // stage zs (z0 -> bf16) and ts
  for (int it = 0; it < 2; ++it) {
    int flat = (it * 1024 + tid) * 4;
    int px = flat >> 7, c = flat & 127;
    float4 v = *(const float4*)&z0[rowbase + flat];
    short tmp[4] = {f2bf(v.x), f2bf(v.y), f2bf(v.z), f2bf(v.w)};
    *(uint2*)&z3s[px * 136 + c] = *(uint2*)tmp;   // zs alias
  }
  const short* tn = tb + (size_t)n * 17408;
  for (int i = tid; i < 2176; i += 1024)
    *(short8*)&R1s[i * 8] = *(const short8*)&tn[i * 8];
  __syncthreads();
  int w = tid >> 6, lane = tid & 63;
  int quad = lane >> 4, r16 = lane & 15;
  int wm = w & 3, wn = w >> 2;
  int strip = wm * 16;
  // phase A: bilinear
  {
    short8 a[4];
#pragma unroll
    for (int kk = 0; kk < 4; ++kk)
      a[kk] = *(const short8*)&z3s[(strip + r16) * 136 + kk * 32 + quad * 8];
#pragma unroll
    for (int nt = 0; nt < 2; ++nt) {
      int o0 = wn * 32 + nt * 16;
      floatx4 acc = {0.f, 0.f, 0.f, 0.f};
#pragma unroll
      for (int kk = 0; kk < 4; ++kk) {
        short8 bfr = *(const short8*)&R1s[(o0 + r16) * 136 + kk * 32 + quad * 8];
        acc = MFMA16(a[kk], bfr, acc);
      }
      float bb = bil_b[o0 + r16];
#pragma unroll
      for (int r = 0; r < 4; ++r) {
        int px = strip + quad * 4 + r;
        z2s[px * 132 + o0 + r16] = acc[r] + bb + xnhwc[rowbase + px * 128 + o0 + r16];
      }
    }
  }
  __syncthreads();
  // LN2: 16 lanes per px -> z3s bf16 (LDS only)
  {
    int px = tid >> 4, cl = tid & 15;
    float4 v0 = *(const float4*)&z2s[px * 132 + cl * 8];
    float4 v1 = *(const float4*)&z2s[px * 132 + cl * 8 + 4];
    float s = v0.x + v0.y + v0.z + v0.w + v1.x + v1.y + v1.z + v1.w;
    float sq = dot4(v0, v0) + dot4(v1, v1);
    s += __shfl_xor(s, 1);  sq += __shfl_xor(sq, 1);
    s += __shfl_xor(s, 2);  sq += __shfl_xor(sq, 2);
    s += __shfl_xor(s, 4);  sq += __shfl_xor(sq, 4);
    s += __shfl_xor(s, 8);  sq += __shfl_xor(sq, 8);
    float m = s * (1.f / 128.f);
    float var = sq * (1.f / 128.f) - m * m;
    float rr = rsqrtf(var + EPS);
    int c0 = cl * 8;
    short t8[8];
#pragma unroll
    for (int j = 0; j < 8; ++j) {
      float vv = (j < 4) ? (&v0.x)[j] : (&v1.x)[j - 4];
      t8[j] = f2bf((vv - m) * rr * g2[c0 + j] + b2ln[c0 + j]);
    }
    *(uint4*)&z3s[px * 136 + c0] = *(uint4*)t8;
  }
  __syncthreads();
  // phase B: FFN
  short8 a3[4];
#pragma unroll
  for (int kk = 0; kk < 4; ++kk)
    a3[kk] = *(const short8*)&z3s[(strip + r16) * 136 + kk * 32 + quad * 8];
  floatx4 zacc[2];
  zacc[0] = (floatx4){0.f, 0.f, 0.f, 0.f};
  zacc[1] = (floatx4){0.f, 0.f, 0.f, 0.f};
  for (int fc = 0; fc < 512; fc += 128) {
    __syncthreads();
    const short* w1src = w1bf + fc * 136;
    const short* w2src = w2bf + (fc >> 7) * 17408;
    for (int i = tid; i < 2176; i += 1024) {
      *(short8*)&R1s[i * 8] = *(const short8*)&w1src[i * 8];   // w1c alias
      *(short8*)&w2c[i * 8] = *(const short8*)&w2src[i * 8];
    }
    __syncthreads();
#pragma unroll
    for (int nt = 0; nt < 2; ++nt) {
      int f0 = wn * 32 + nt * 16;
      floatx4 acc = {0.f, 0.f, 0.f, 0.f};
#pragma unroll
      for (int kk = 0; kk < 4; ++kk) {
        short8 bfr = *(const short8*)&R1s[(f0 + r16) * 136 + kk * 32 + quad * 8];
        acc = MFMA16(a3[kk], bfr, acc);
      }
      float bb1 = b1[fc + f0 + r16];
#pragma unroll
      for (int r = 0; r < 4; ++r) {
        float hv = acc[r] + bb1;
        float ge = 0.5f * hv * (1.f + erff(hv * 0.70710678118f));
        h1s[(strip + quad * 4 + r) * 136 + f0 + r16] = f2bf(ge);
      }
    }
    __syncthreads();
    short8 ah[4];
#pragma unroll
    for (int kk = 0; kk < 4; ++kk)
      ah[kk] = *(const short8*)&h1s[(strip + r16) * 136 + kk * 32 + quad * 8];
#pragma unroll
    for (int nt = 0; nt < 2; ++nt) {
      int o0 = wn * 32 + nt * 16;
#pragma unroll
      for (int kk = 0; kk < 4; ++kk) {
        short8 bfr = *(const short8*)&w2c[(o0 + r16) * 136 + kk * 32 + quad * 8];
        zacc[nt] = MFMA16(ah[kk], bfr, zacc[nt]);
      }
    }
  }
  __syncthreads();  // done with w1c region -> outt alias safe
  // epilogue: + b2 + z2 residual (LDS), transpose via LDS, coalesced NCHW store
#pragma unroll
  for (int nt = 0; nt < 2; ++nt) {
    int o0 = wn * 32 + nt * 16;
    float bb = b2[o0 + r16];
#pragma unroll
    for (int r = 0; r < 4; ++r) {
      int px = strip + quad * 4 + r;
      outt[(o0 + r16) * 65 + px] = zacc[nt][r] + bb + z2s[px * 132 + o0 + r16];
    }
  }
  __syncthreads();
  for (int it = 0; it < 8; ++it) {
    int flat = it * 1024 + tid;   // o*64 + px
    int o = flat >> 6, px = flat & 63;
    out[(((size_t)(n * 128 + o)) * 64 + y) * 64 + px] = outt[o * 65 + px];
  }
}

// ----------------------------------------------------------------
extern "C" void kernel_launch(void* const* d_in, const int* in_sizes, int n_in,
                              void* d_out, int out_size, void* d_ws, size_t ws_size,
                              hipStream_t stream) {
  const float* x        = (const float*)d_in[0];
  const float* qcoeff   = (const float*)d_in[1];
  const float* wq       = (const float*)d_in[2];
  const float* bq       = (const float*)d_in[3];
  const float* wk       = (const float*)d_in[4];
  const float* bk       = (const float*)d_in[5];
  const float* wv       = (const float*)d_in[6];
  const float* bv       = (const float*)d_in[7];
  const float* rel_bias = (const float*)d_in[8];
  const float* ln1_g    = (const float*)d_in[9];
  const float* ln1_b    = (const float*)d_in[10];
  const float* bil_w    = (const float*)d_in[11];
  const float* bil_b    = (const float*)d_in[12];
  const float* ln2_g    = (const float*)d_in[13];
  const float* ln2_b    = (const float*)d_in[14];
  const float* w1       = (const float*)d_in[15];
  const float* b1       = (const float*)d_in[16];
  const float* w2       = (const float*)d_in[17];
  const float* b2       = (const float*)d_in[18];
  float* out = (float*)d_out;

  float* ws = (float*)d_ws;
  float* x_nhwc = ws;                    // [N,H,W,E] fp32 (residual source)
  float* z0     = ws + 1 * SZ;           // attention output fp32
  short* qbf = (short*)(ws + 2 * SZ);    // bf16 NHWC
  short* kbf = qbf + SZ;                 // bf16 NHWC
  short* vtb = kbf + SZ;                 // bf16 transposed [n*128+o][4096]
  short* bf     = (short*)(ws + 4 * SZ); // bf16 weights
  short* tb     = bf;                    // [4][128][136]
  short* w1bf   = bf + 4 * 17408;        // [512][136]
  short* w2bf   = w1bf + 512 * 136;      // [4][128][136]
  short* wqbf   = w2bf + 4 * 17408;      // [128][136]
  short* wkbf   = wqbf + 17408;
  short* wvbf   = wkbf + 17408;

  k_prep<<<64, 256, 0, stream>>>(w1, w2, wq, wk, wv, bil_w, qcoeff,
                                 w1bf, w2bf, wqbf, wkbf, wvbf, tb);
  k_qkvln<<<256, 1024, 0, stream>>>(x, ln1_g, ln1_b, wqbf, wkbf, wvbf,
                                    bq, bk, bv, x_nhwc, qbf, kbf, vtb);
  k_attn<<<1024, 256, 0, stream>>>(qbf, kbf, vtb, rel_bias, z0);
  k_tail<<<256, 1024, 0, stream>>>(z0, tb, bil_b, x_nhwc, ln2_g, ln2_b,
                                   w1bf, b1, w2bf, b2, out);
}